// Round 4
// baseline (169.131 us; speedup 1.0000x reference)
//
#include <hip/hip_runtime.h>

#define NI 4096
#define NH 8192
#define NO 2048

typedef float  f4 __attribute__((ext_vector_type(4)));
typedef unsigned short u16x8 __attribute__((ext_vector_type(8)));
typedef unsigned int   u32x2 __attribute__((ext_vector_type(2)));

__device__ __forceinline__ float apply_act(float x, int id) {
    switch (id) {
        case 0:  return x;
        case 1:  return x >= 0.f ? x : 0.01f * x;   // leaky_relu
        case 2:  return fmaxf(x, 0.f);              // relu
        case 3:  return 1.f / (1.f + expf(-x));     // sigmoid
        default: return tanhf(x);                   // tanh
    }
}

// round-to-nearest-even fp32 -> bf16 payload
__device__ __forceinline__ unsigned int f2bf(float f) {
    unsigned int u = __float_as_uint(f);
    return (u + 0x7FFFu + ((u >> 16) & 1u)) >> 16;
}
__device__ __forceinline__ float bf2f(unsigned int b) {
    return __uint_as_float(b << 16);
}

// One 64-lane wave computes dot(Wrow, x) in fp32. NT = non-temporal stream.
template <bool NT>
__device__ __forceinline__ float wave_dot(const float* __restrict__ Wrow,
                                          const float* __restrict__ x,
                                          int K, int lane) {
    const f4* __restrict__ W4 = (const f4*)Wrow;
    const f4* __restrict__ x4 = (const f4*)x;
    float acc = 0.f;
    const int n4 = K >> 2;
    #pragma unroll 4
    for (int i = lane; i < n4; i += 64) {
        f4 w = NT ? __builtin_nontemporal_load(W4 + i) : W4[i];
        f4 v = x4[i];
        acc = fmaf(w.x, v.x, acc);
        acc = fmaf(w.y, v.y, acc);
        acc = fmaf(w.z, v.z, acc);
        acc = fmaf(w.w, v.w, acc);
    }
    #pragma unroll
    for (int off = 32; off; off >>= 1) acc += __shfl_xor(acc, off, 64);
    return acc;
}

// Wave dot with bf16 weight row (16B loads), fp32 x and accumulation.
// Normal (cached) loads: these rows should be L3-resident.
__device__ __forceinline__ float wave_dot_bf(const unsigned short* __restrict__ Wrow,
                                             const float* __restrict__ x,
                                             int K, int lane) {
    const u16x8* __restrict__ W8 = (const u16x8*)Wrow;
    const f4* __restrict__ x4 = (const f4*)x;
    float acc = 0.f;
    const int n8 = K >> 3;
    #pragma unroll 4
    for (int i = lane; i < n8; i += 64) {
        u16x8 w = W8[i];
        f4 va = x4[2 * i];
        f4 vb = x4[2 * i + 1];
        acc = fmaf(bf2f(w[0]), va.x, acc);
        acc = fmaf(bf2f(w[1]), va.y, acc);
        acc = fmaf(bf2f(w[2]), va.z, acc);
        acc = fmaf(bf2f(w[3]), va.w, acc);
        acc = fmaf(bf2f(w[4]), vb.x, acc);
        acc = fmaf(bf2f(w[5]), vb.y, acc);
        acc = fmaf(bf2f(w[6]), vb.z, acc);
        acc = fmaf(bf2f(w[7]), vb.w, acc);
    }
    #pragma unroll
    for (int off = 32; off; off >>= 1) acc += __shfl_xor(acc, off, 64);
    return acc;
}

// Single block: flags[i] = any(vec_i != 0)
__global__ __launch_bounds__(256) void k_flags(const float* __restrict__ xin,
                                               const float* __restrict__ a0,
                                               const float* __restrict__ o0,
                                               int* __restrict__ flags) {
    __shared__ int s[3];
    int t = threadIdx.x;
    if (t < 3) s[t] = 0;
    __syncthreads();
    int f0 = 0, f1 = 0, f2 = 0;
    for (int i = t; i < NI; i += 256) f0 |= (xin[i] != 0.f);
    for (int i = t; i < NH; i += 256) f1 |= (a0[i]  != 0.f);
    for (int i = t; i < NO; i += 256) f2 |= (o0[i]  != 0.f);
    if (f0) atomicOr(&s[0], 1);
    if (f1) atomicOr(&s[1], 1);
    if (f2) atomicOr(&s[2], 1);
    __syncthreads();
    if (t < 3) flags[t] = s[t];
}

// Fused: c_h = i2h·x + o2h·o0 (loop-invariant), step-1 epilogue, AND the
// one-time fp32->bf16 conversion of W_h2h into Wb (normal stores -> the
// 128 MiB copy lands in the 256 MiB L3 for steps 2 and 3 to hit).
__global__ __launch_bounds__(256) void k_h_init_conv(const float* __restrict__ W_i2h,
                                                     const float* __restrict__ W_o2h,
                                                     const float* __restrict__ W_h2h,
                                                     const float* __restrict__ xin,
                                                     const float* __restrict__ o0,
                                                     const float* __restrict__ a0,
                                                     const float* __restrict__ resp,
                                                     const float* __restrict__ bias,
                                                     const int* __restrict__ ids,
                                                     const int* __restrict__ flags,
                                                     float* __restrict__ c_h,
                                                     float* __restrict__ act_a,
                                                     unsigned short* __restrict__ Wb) {
    int wave = threadIdx.x >> 6;
    int lane = threadIdx.x & 63;
    int m = blockIdx.x * 4 + wave;

    // --- W_h2h row: NT fp32 read, bf16 convert+store, step-1 dot (fp32) ---
    const f4* __restrict__ W4 = (const f4*)(W_h2h + (size_t)m * NH);
    const f4* __restrict__ a4 = (const f4*)a0;
    u32x2* __restrict__ B2 = (u32x2*)(Wb + (size_t)m * NH);
    float d = 0.f;
    #pragma unroll 4
    for (int i = lane; i < NH / 4; i += 64) {
        f4 w = __builtin_nontemporal_load(W4 + i);
        f4 v = a4[i];
        d = fmaf(w.x, v.x, d);
        d = fmaf(w.y, v.y, d);
        d = fmaf(w.z, v.z, d);
        d = fmaf(w.w, v.w, d);
        u32x2 b;
        b.x = f2bf(w.x) | (f2bf(w.y) << 16);
        b.y = f2bf(w.z) | (f2bf(w.w) << 16);
        B2[i] = b;
    }
    #pragma unroll
    for (int off = 32; off; off >>= 1) d += __shfl_xor(d, off, 64);

    // --- loop-invariant part ---
    float c = 0.f;
    if (flags[0]) c += wave_dot<true>(W_i2h + (size_t)m * NI, xin, NI, lane);
    if (flags[2]) c += wave_dot<true>(W_o2h + (size_t)m * NO, o0,  NO, lane);

    if (lane == 0) {
        c_h[m] = c;
        float dd = flags[1] ? d : 0.f;
        act_a[m] = apply_act(fmaf(resp[m], c + dd, bias[m]), ids[m]);
    }
}

// Hidden step from the bf16 copy (expected L3-resident).
__global__ __launch_bounds__(256) void k_step_bf(const unsigned short* __restrict__ Wb,
                                                 const float* __restrict__ x,
                                                 const float* __restrict__ c_h,
                                                 const float* __restrict__ resp,
                                                 const float* __restrict__ bias,
                                                 const int* __restrict__ ids,
                                                 float* __restrict__ out) {
    int wave = threadIdx.x >> 6;
    int lane = threadIdx.x & 63;
    int m = blockIdx.x * 4 + wave;
    float dot = wave_dot_bf(Wb + (size_t)m * NH, x, NH, lane);
    if (lane == 0) {
        float pre = fmaf(resp[m], c_h[m] + dot, bias[m]);
        out[m] = apply_act(pre, ids[m]);
    }
}

// fp32 fallback (ws too small for the bf16 copy): R2 structure.
__global__ __launch_bounds__(256) void k_h_init(const float* __restrict__ W_i2h,
                                                const float* __restrict__ W_o2h,
                                                const float* __restrict__ W_h2h,
                                                const float* __restrict__ xin,
                                                const float* __restrict__ o0,
                                                const float* __restrict__ a0,
                                                const float* __restrict__ resp,
                                                const float* __restrict__ bias,
                                                const int* __restrict__ ids,
                                                const int* __restrict__ flags,
                                                float* __restrict__ c_h,
                                                float* __restrict__ act_a) {
    int wave = threadIdx.x >> 6;
    int lane = threadIdx.x & 63;
    int m = blockIdx.x * 4 + wave;
    float c = 0.f;
    if (flags[0]) c += wave_dot<true>(W_i2h + (size_t)m * NI, xin, NI, lane);
    if (flags[2]) c += wave_dot<true>(W_o2h + (size_t)m * NO, o0,  NO, lane);
    float d = 0.f;
    if (flags[1]) d = wave_dot<false>(W_h2h + (size_t)m * NH, a0, NH, lane);
    if (lane == 0) {
        c_h[m] = c;
        act_a[m] = apply_act(fmaf(resp[m], c + d, bias[m]), ids[m]);
    }
}

template <int REV>
__global__ __launch_bounds__(256) void k_step(const float* __restrict__ W_h2h,
                                              const float* __restrict__ x,
                                              const float* __restrict__ c_h,
                                              const float* __restrict__ resp,
                                              const float* __restrict__ bias,
                                              const int* __restrict__ ids,
                                              float* __restrict__ out) {
    int wave = threadIdx.x >> 6;
    int lane = threadIdx.x & 63;
    int m = blockIdx.x * 4 + wave;
    if (REV) m = (NH - 1) - m;
    float dot = wave_dot<false>(W_h2h + (size_t)m * NH, x, NH, lane);
    if (lane == 0) {
        float pre = fmaf(resp[m], c_h[m] + dot, bias[m]);
        out[m] = apply_act(pre, ids[m]);
    }
}

// Output layer: all weights single-use -> non-temporal.
__global__ __launch_bounds__(256) void k_final(const float* __restrict__ W_i2o,
                                               const float* __restrict__ W_o2o,
                                               const float* __restrict__ W_h2o,
                                               const float* __restrict__ xin,
                                               const float* __restrict__ o0,
                                               const float* __restrict__ act,
                                               const float* __restrict__ resp,
                                               const float* __restrict__ bias,
                                               const int* __restrict__ ids,
                                               const int* __restrict__ flags,
                                               float* __restrict__ out) {
    int wave = threadIdx.x >> 6;
    int lane = threadIdx.x & 63;
    int m = blockIdx.x * 4 + wave;
    float dot = wave_dot<true>(W_h2o + (size_t)m * NH, act, NH, lane);
    if (flags[0]) dot += wave_dot<true>(W_i2o + (size_t)m * NI, xin, NI, lane);
    if (flags[2]) dot += wave_dot<true>(W_o2o + (size_t)m * NO, o0,  NO, lane);
    if (lane == 0) {
        float pre = fmaf(resp[m], dot, bias[m]);
        out[m] = apply_act(pre, ids[m]);
    }
}

extern "C" void kernel_launch(void* const* d_in, const int* in_sizes, int n_in,
                              void* d_out, int out_size, void* d_ws, size_t ws_size,
                              hipStream_t stream) {
    const float* inputs   = (const float*)d_in[0];
    const float* W_i2h    = (const float*)d_in[1];
    const float* W_h2h    = (const float*)d_in[2];
    const float* W_o2h    = (const float*)d_in[3];
    const float* W_i2o    = (const float*)d_in[4];
    const float* W_h2o    = (const float*)d_in[5];
    const float* W_o2o    = (const float*)d_in[6];
    const float* h_resp   = (const float*)d_in[7];
    const float* h_bias   = (const float*)d_in[8];
    const float* o_resp   = (const float*)d_in[9];
    const float* o_bias   = (const float*)d_in[10];
    const float* activs0  = (const float*)d_in[11];
    const float* outputs0 = (const float*)d_in[12];
    const int*   h_ids    = (const int*)d_in[13];
    const int*   o_ids    = (const int*)d_in[14];

    float* ws    = (float*)d_ws;
    float* c_h   = ws;            // NH floats
    float* act_a = ws + NH;       // NH floats
    float* act_b = ws + 2 * NH;   // NH floats
    int*   flags = (int*)(ws + 3 * NH);   // 3 ints (+pad)

    size_t bf_off = (((size_t)(3 * NH + 4) * sizeof(float)) + 255) & ~(size_t)255;
    unsigned short* Wb = (unsigned short*)((char*)d_ws + bf_off);
    bool use_bf = ws_size >= bf_off + (size_t)NH * NH * sizeof(unsigned short);

    k_flags<<<1, 256, 0, stream>>>(inputs, activs0, outputs0, flags);

    if (use_bf) {
        // c_h + step 1 + one-time bf16 conversion of W_h2h
        k_h_init_conv<<<NH / 4, 256, 0, stream>>>(W_i2h, W_o2h, W_h2h, inputs,
                                                  outputs0, activs0, h_resp, h_bias,
                                                  h_ids, flags, c_h, act_a, Wb);
        // steps 2 and 3 both read the (L3-resident) bf16 copy
        k_step_bf<<<NH / 4, 256, 0, stream>>>(Wb, act_a, c_h, h_resp, h_bias,
                                              h_ids, act_b);
        k_step_bf<<<NH / 4, 256, 0, stream>>>(Wb, act_b, c_h, h_resp, h_bias,
                                              h_ids, act_a);
    } else {
        k_h_init<<<NH / 4, 256, 0, stream>>>(W_i2h, W_o2h, W_h2h, inputs, outputs0,
                                             activs0, h_resp, h_bias, h_ids, flags,
                                             c_h, act_a);
        k_step<0><<<NH / 4, 256, 0, stream>>>(W_h2h, act_a, c_h, h_resp, h_bias,
                                              h_ids, act_b);
        k_step<1><<<NH / 4, 256, 0, stream>>>(W_h2h, act_b, c_h, h_resp, h_bias,
                                              h_ids, act_a);
    }

    k_final<<<NO / 4, 256, 0, stream>>>(W_i2o, W_o2o, W_h2o, inputs, outputs0, act_a,
                                        o_resp, o_bias, o_ids, flags, (float*)d_out);
}

// Round 5
// 155.475 us; speedup vs baseline: 1.0878x; 1.0878x over previous
//
#include <hip/hip_runtime.h>

#define NI 4096
#define NH 8192
#define NO 2048

typedef float f4 __attribute__((ext_vector_type(4)));

__device__ __forceinline__ float apply_act(float x, int id) {
    switch (id) {
        case 0:  return x;
        case 1:  return x >= 0.f ? x : 0.01f * x;   // leaky_relu
        case 2:  return fmaxf(x, 0.f);              // relu
        case 3:  return 1.f / (1.f + expf(-x));     // sigmoid
        default: return tanhf(x);                   // tanh
    }
}

// One 64-lane wave: dot(Wrow, x) over K fp32 elems, float4 loads.
template <bool NT>
__device__ __forceinline__ float wave_dot(const float* __restrict__ Wrow,
                                          const float* __restrict__ x,
                                          int K, int lane) {
    const f4* __restrict__ W4 = (const f4*)Wrow;
    const f4* __restrict__ x4 = (const f4*)x;
    float acc = 0.f;
    const int n4 = K >> 2;
    #pragma unroll 4
    for (int i = lane; i < n4; i += 64) {
        f4 w = NT ? __builtin_nontemporal_load(W4 + i) : W4[i];
        f4 v = x4[i];
        acc = fmaf(w.x, v.x, acc);
        acc = fmaf(w.y, v.y, acc);
        acc = fmaf(w.z, v.z, acc);
        acc = fmaf(w.w, v.w, acc);
    }
    #pragma unroll
    for (int off = 32; off; off >>= 1) acc += __shfl_xor(acc, off, 64);
    return acc;
}

// Two rows per wave sharing the x loads; both accs valid in all lanes.
template <bool NT>
__device__ __forceinline__ void wave_dot2(const float* __restrict__ Wr0,
                                          const float* __restrict__ Wr1,
                                          const float* __restrict__ x,
                                          int K, int lane,
                                          float& d0, float& d1) {
    const f4* __restrict__ W0 = (const f4*)Wr0;
    const f4* __restrict__ W1 = (const f4*)Wr1;
    const f4* __restrict__ x4 = (const f4*)x;
    float a0 = 0.f, a1 = 0.f;
    const int n4 = K >> 2;
    #pragma unroll 4
    for (int i = lane; i < n4; i += 64) {
        f4 v = x4[i];
        f4 w0 = NT ? __builtin_nontemporal_load(W0 + i) : W0[i];
        f4 w1 = NT ? __builtin_nontemporal_load(W1 + i) : W1[i];
        a0 = fmaf(w0.x, v.x, a0); a0 = fmaf(w0.y, v.y, a0);
        a0 = fmaf(w0.z, v.z, a0); a0 = fmaf(w0.w, v.w, a0);
        a1 = fmaf(w1.x, v.x, a1); a1 = fmaf(w1.y, v.y, a1);
        a1 = fmaf(w1.z, v.z, a1); a1 = fmaf(w1.w, v.w, a1);
    }
    #pragma unroll
    for (int off = 32; off; off >>= 1) {
        a0 += __shfl_xor(a0, off, 64);
        a1 += __shfl_xor(a1, off, 64);
    }
    d0 = a0; d1 = a1;
}

// Single block: flags[i] = any(vec_i != 0)
__global__ __launch_bounds__(256) void k_flags(const float* __restrict__ xin,
                                               const float* __restrict__ a0,
                                               const float* __restrict__ o0,
                                               int* __restrict__ flags) {
    __shared__ int s[3];
    int t = threadIdx.x;
    if (t < 3) s[t] = 0;
    __syncthreads();
    int f0 = 0, f1 = 0, f2 = 0;
    for (int i = t; i < NI; i += 256) f0 |= (xin[i] != 0.f);
    for (int i = t; i < NH; i += 256) f1 |= (a0[i]  != 0.f);
    for (int i = t; i < NO; i += 256) f2 |= (o0[i]  != 0.f);
    if (f0) atomicOr(&s[0], 1);
    if (f1) atomicOr(&s[1], 1);
    if (f2) atomicOr(&s[2], 1);
    __syncthreads();
    if (t < 3) flags[t] = s[t];
}

// c_h[m] = i2h·x + o2h·o0 (loop-invariant) + step-1 epilogue.
__global__ __launch_bounds__(256) void k_h_init(const float* __restrict__ W_i2h,
                                                const float* __restrict__ W_o2h,
                                                const float* __restrict__ W_h2h,
                                                const float* __restrict__ xin,
                                                const float* __restrict__ o0,
                                                const float* __restrict__ a0,
                                                const float* __restrict__ resp,
                                                const float* __restrict__ bias,
                                                const int* __restrict__ ids,
                                                const int* __restrict__ flags,
                                                float* __restrict__ c_h,
                                                float* __restrict__ act_a) {
    int wave = threadIdx.x >> 6;
    int lane = threadIdx.x & 63;
    int m = blockIdx.x * 4 + wave;
    float c = 0.f;
    if (flags[0]) c += wave_dot<true>(W_i2h + (size_t)m * NI, xin, NI, lane);
    if (flags[2]) c += wave_dot<true>(W_o2h + (size_t)m * NO, o0,  NO, lane);
    float d = 0.f;
    if (flags[1]) d = wave_dot<false>(W_h2h + (size_t)m * NH, a0, NH, lane);
    if (lane == 0) {
        c_h[m] = c;
        act_a[m] = apply_act(fmaf(resp[m], c + d, bias[m]), ids[m]);
    }
}

// Hidden step, 2 rows/wave. STEP=0: forward order, rows < NH/2 NT, upper
// half normal-cached (leaves the freshest 128 MiB in LLC). STEP=1: reversed
// order (upper half first -> LLC hits if read-retention works), lower NT.
template <int STEP>
__global__ __launch_bounds__(256) void k_step(const float* __restrict__ W_h2h,
                                              const float* __restrict__ x,
                                              const float* __restrict__ c_h,
                                              const float* __restrict__ resp,
                                              const float* __restrict__ bias,
                                              const int* __restrict__ ids,
                                              float* __restrict__ out) {
    int wave = threadIdx.x >> 6;
    int lane = threadIdx.x & 63;
    int pair = blockIdx.x * 4 + wave;          // 0 .. NH/2-1
    int m0 = 2 * pair;
    if (STEP == 1) m0 = (NH - 2) - m0;         // reversed: highest pair first
    int m1 = m0 + 1;
    float d0, d1;
    if (m0 < NH / 2) {
        wave_dot2<true >(W_h2h + (size_t)m0 * NH, W_h2h + (size_t)m1 * NH,
                         x, NH, lane, d0, d1);
    } else {
        wave_dot2<false>(W_h2h + (size_t)m0 * NH, W_h2h + (size_t)m1 * NH,
                         x, NH, lane, d0, d1);
    }
    if (lane == 0) {
        out[m0] = apply_act(fmaf(resp[m0], c_h[m0] + d0, bias[m0]), ids[m0]);
        out[m1] = apply_act(fmaf(resp[m1], c_h[m1] + d1, bias[m1]), ids[m1]);
    }
}

// Output layer, split-K x2: 4 waves/block, 2 rows/block, LDS combine.
__global__ __launch_bounds__(256) void k_final(const float* __restrict__ W_i2o,
                                               const float* __restrict__ W_o2o,
                                               const float* __restrict__ W_h2o,
                                               const float* __restrict__ xin,
                                               const float* __restrict__ o0,
                                               const float* __restrict__ act,
                                               const float* __restrict__ resp,
                                               const float* __restrict__ bias,
                                               const int* __restrict__ ids,
                                               const int* __restrict__ flags,
                                               float* __restrict__ out) {
    __shared__ float part[4];
    int wave = threadIdx.x >> 6;
    int lane = threadIdx.x & 63;
    int rloc = wave >> 1;          // 0,1: row within block
    int kh   = wave & 1;           // 0,1: K-half
    int m = blockIdx.x * 2 + rloc;
    float acc = wave_dot<true>(W_h2o + (size_t)m * NH + kh * (NH / 2),
                               act + kh * (NH / 2), NH / 2, lane);
    if (kh == 0 && flags[0])
        acc += wave_dot<true>(W_i2o + (size_t)m * NI, xin, NI, lane);
    if (kh == 1 && flags[2])
        acc += wave_dot<true>(W_o2o + (size_t)m * NO, o0, NO, lane);
    if (lane == 0) part[wave] = acc;
    __syncthreads();
    if (kh == 0 && lane == 0) {
        float dot = part[wave] + part[wave + 1];
        out[m] = apply_act(fmaf(resp[m], dot, bias[m]), ids[m]);
    }
}

extern "C" void kernel_launch(void* const* d_in, const int* in_sizes, int n_in,
                              void* d_out, int out_size, void* d_ws, size_t ws_size,
                              hipStream_t stream) {
    const float* inputs   = (const float*)d_in[0];
    const float* W_i2h    = (const float*)d_in[1];
    const float* W_h2h    = (const float*)d_in[2];
    const float* W_o2h    = (const float*)d_in[3];
    const float* W_i2o    = (const float*)d_in[4];
    const float* W_h2o    = (const float*)d_in[5];
    const float* W_o2o    = (const float*)d_in[6];
    const float* h_resp   = (const float*)d_in[7];
    const float* h_bias   = (const float*)d_in[8];
    const float* o_resp   = (const float*)d_in[9];
    const float* o_bias   = (const float*)d_in[10];
    const float* activs0  = (const float*)d_in[11];
    const float* outputs0 = (const float*)d_in[12];
    const int*   h_ids    = (const int*)d_in[13];
    const int*   o_ids    = (const int*)d_in[14];

    float* ws    = (float*)d_ws;
    float* c_h   = ws;            // NH floats
    float* act_a = ws + NH;       // NH floats
    float* act_b = ws + 2 * NH;   // NH floats
    int*   flags = (int*)(ws + 3 * NH);

    k_flags<<<1, 256, 0, stream>>>(inputs, activs0, outputs0, flags);

    k_h_init<<<NH / 4, 256, 0, stream>>>(W_i2h, W_o2h, W_h2h, inputs, outputs0,
                                         activs0, h_resp, h_bias, h_ids, flags,
                                         c_h, act_a);
    // step 2: forward, upper half cached in LLC
    k_step<0><<<NH / 8, 256, 0, stream>>>(W_h2h, act_a, c_h, h_resp, h_bias, h_ids,
                                          act_b);
    // step 3: reversed, upper half first (LLC hits if retention works)
    k_step<1><<<NH / 8, 256, 0, stream>>>(W_h2h, act_b, c_h, h_resp, h_bias, h_ids,
                                          act_a);

    k_final<<<NO / 2, 256, 0, stream>>>(W_i2o, W_o2o, W_h2o, inputs, outputs0, act_a,
                                        o_resp, o_bias, o_ids, flags, (float*)d_out);
}